// Round 3
// baseline (236.684 us; speedup 1.0000x reference)
//
#include <hip/hip_runtime.h>
#include <hip/hip_bf16.h>

#define BB 8
#define LL 4096
#define NCH 8192
#define IDIM 256
#define KDIM 512
#define ODIM 512
#define NDIR 6
#define TOT (BB * LL)  // 32768

typedef short short8 __attribute__((ext_vector_type(8)));
typedef float floatx4 __attribute__((ext_vector_type(4)));

// ws layout:
//   ints [0..7]   cnt per dir
//   ints [8..15]  fill cursors
//   ints [16..23] base (exclusive scan)
//   ints [64 .. 64+TOT)        idx  (lin per bucketed row)
//   ints [64+TOT .. 64+2*TOT)  rows (r0 | r1<<16)
//   bytes 262400..: bf16 copy of last (16,777,216 elems = 33.5 MB)
//   then: bf16 copy of W (1,572,864 elems = 3.1 MB)
// total ~= 37 MB

#define WS_LAST_OFF (64 + 2 * TOT)                 // in ints
#define LAST_ELEMS (BB * NCH * IDIM)               // 16,777,216
#define W_ELEMS (NDIR * ODIM * KDIM)               // 1,572,864

// ---------------- fp32 -> bf16 streaming cast (8 elems/thread) ----------------
__global__ __launch_bounds__(256) void cvt_kernel(const float* __restrict__ src,
                                                  __hip_bfloat16* __restrict__ dst,
                                                  int n8) {
  int i = blockIdx.x * 256 + threadIdx.x;
  if (i >= n8) return;
  const floatx4* s = (const floatx4*)src;
  floatx4 a = s[2 * i];
  floatx4 b = s[2 * i + 1];
  union { short8 v; __hip_bfloat16 h[8]; } u;
  u.h[0] = __float2bfloat16(a[0]); u.h[1] = __float2bfloat16(a[1]);
  u.h[2] = __float2bfloat16(a[2]); u.h[3] = __float2bfloat16(a[3]);
  u.h[4] = __float2bfloat16(b[0]); u.h[5] = __float2bfloat16(b[1]);
  u.h[6] = __float2bfloat16(b[2]); u.h[7] = __float2bfloat16(b[3]);
  ((short8*)dst)[i] = u.v;
}

// ---------------- Kernel 1: histogram ----------------
__global__ __launch_bounds__(256) void count_kernel(
    const int* __restrict__ vec, const int* __restrict__ dmap,
    int* __restrict__ ws) {
  __shared__ int lcnt[8];
  int tid = threadIdx.x;
  if (tid < 8) lcnt[tid] = 0;
  __syncthreads();
  int lin = blockIdx.x * 256 + tid;
  int dir = dmap[vec[lin]] & 7;
  atomicAdd(&lcnt[dir], 1);
  __syncthreads();
  if (tid < 8 && lcnt[tid]) atomicAdd(&ws[tid], lcnt[tid]);
}

// ---------------- Kernel 2: 8-entry exclusive scan ----------------
__global__ void scan_kernel(int* __restrict__ ws) {
  if (threadIdx.x == 0) {
    int s = 0;
    for (int d = 0; d < 8; ++d) { ws[16 + d] = s; s += ws[d]; }
  }
}

// ---------------- Kernel 3: scatter into compact buckets ----------------
__global__ __launch_bounds__(256) void scatter_kernel(
    const int* __restrict__ vec, const int* __restrict__ child_l,
    const int* __restrict__ child_r, const int* __restrict__ drev,
    const int* __restrict__ dmap, int* __restrict__ ws) {
  __shared__ int lcnt[8];
  __shared__ int gbase[8];
  int* fill = ws + 8;
  const int* base = ws + 16;
  int* idx = ws + 64;
  int* rows = ws + 64 + TOT;

  int tid = threadIdx.x;
  if (tid < 8) lcnt[tid] = 0;
  __syncthreads();

  int lin = blockIdx.x * 256 + tid;
  int l = lin & (LL - 1);
  int v = vec[lin];
  int dir = dmap[v] & 7;
  int sw = drev[v];
  int cl = child_l[l];
  int cr = child_r[l];
  int r0 = sw ? cr : cl;  // first half of x (a in reference)
  int r1 = sw ? cl : cr;  // second half (b in reference)
  int pos = atomicAdd(&lcnt[dir], 1);
  __syncthreads();
  if (tid < 8) gbase[tid] = lcnt[tid] ? atomicAdd(&fill[tid], lcnt[tid]) : 0;
  __syncthreads();
  int slot = base[dir] + gbase[dir] + pos;
  idx[slot] = lin;
  rows[slot] = r0 | (r1 << 16);
}

// ---------------- Kernel 4: grouped GEMM via MFMA (bf16 staged inputs) --------
// Block = 256 threads = 4 waves (2x2). Each wave: 64x64 output tile via
// 4x4 grid of mfma_f32_16x16x32_bf16. Register-direct fragment loads.
__global__ __launch_bounds__(256) void gemm_kernel(
    const float* __restrict__ bias, const float* __restrict__ alpha_m,
    const int* __restrict__ ws, float* __restrict__ out) {
  const int d = blockIdx.z;
  const int mt = blockIdx.y;
  const int nt = blockIdx.x;
  const int count = ws[d];
  if (mt * 128 >= count) return;
  const int off = ws[16 + d];
  const int* idx = ws + 64;
  const int* rows = ws + 64 + TOT;
  const __hip_bfloat16* last = (const __hip_bfloat16*)(ws + WS_LAST_OFF);
  const __hip_bfloat16* W = last + LAST_ELEMS;

  const int tid = threadIdx.x;
  const int wave = tid >> 6;
  const int lane = tid & 63;
  const int wm = wave >> 1;  // m half of block tile
  const int wn = wave & 1;   // n half
  const int lane15 = lane & 15;
  const int quad = lane >> 4;

  const int m_base = mt * 128 + wm * 64;
  const int n_base = nt * 128 + wn * 64;

  // Per-fragment A row base pointers (gathered rows; lane15 = m within frag)
  const __hip_bfloat16* abase0[4];
  const __hip_bfloat16* abase1[4];
#pragma unroll
  for (int i = 0; i < 4; ++i) {
    int row_id = m_base + i * 16 + lane15;
    int rid = row_id < count ? row_id : 0;
    int lin = idx[off + rid] & (TOT - 1);
    int rr = rows[off + rid];
    int b = lin >> 12;  // L = 4096
    int r0 = rr & (NCH - 1);
    int r1 = (rr >> 16) & (NCH - 1);
    abase0[i] = last + (long long)(b * NCH + r0) * IDIM;
    abase1[i] = last + (long long)(b * NCH + r1) * IDIM;
  }
  // B (W) row base pointers (lane15 = n within frag)
  const __hip_bfloat16* bbase[4];
#pragma unroll
  for (int j = 0; j < 4; ++j) {
    int n = n_base + j * 16 + lane15;
    bbase[j] = W + ((long long)d * ODIM + n) * KDIM;
  }

  floatx4 acc[4][4] = {};

  const int koff = quad * 8;  // k offset within 32-wide k-step for this lane
#pragma unroll
  for (int kt = 0; kt < 16; ++kt) {
    const int k0 = kt * 32;
    short8 a[4], bf[4];
#pragma unroll
    for (int i = 0; i < 4; ++i) {
      const __hip_bfloat16* base = (k0 < 256) ? abase0[i] : abase1[i];
      a[i] = *(const short8*)(base + (k0 & 255) + koff);
    }
#pragma unroll
    for (int j = 0; j < 4; ++j) {
      bf[j] = *(const short8*)(bbase[j] + k0 + koff);
    }
#pragma unroll
    for (int i = 0; i < 4; ++i)
#pragma unroll
      for (int j = 0; j < 4; ++j)
        acc[i][j] = __builtin_amdgcn_mfma_f32_16x16x32_bf16(a[i], bf[j], acc[i][j], 0, 0, 0);
  }

  // Epilogue: bias + leaky relu (fp32), scatter rows by lin.
  const float alpha = alpha_m[d];
  float bj[4];
#pragma unroll
  for (int j = 0; j < 4; ++j)
    bj[j] = bias[d * ODIM + n_base + j * 16 + lane15];

#pragma unroll
  for (int i = 0; i < 4; ++i) {
#pragma unroll
    for (int reg = 0; reg < 4; ++reg) {
      int row_id = m_base + i * 16 + quad * 4 + reg;
      if (row_id >= count) continue;
      int lin = idx[off + row_id] & (TOT - 1);
      float* orow = out + (long long)lin * ODIM + n_base;
#pragma unroll
      for (int j = 0; j < 4; ++j) {
        float y = acc[i][j][reg] + bj[j];
        y = y > 0.f ? y : alpha * y;
        orow[j * 16 + lane15] = y;
      }
    }
  }
}

extern "C" void kernel_launch(void* const* d_in, const int* in_sizes, int n_in,
                              void* d_out, int out_size, void* d_ws, size_t ws_size,
                              hipStream_t stream) {
  const float* last = (const float*)d_in[0];
  const float* W = (const float*)d_in[1];
  const float* bias = (const float*)d_in[2];
  const float* alpha = (const float*)d_in[3];
  const int* child_l = (const int*)d_in[4];
  const int* child_r = (const int*)d_in[5];
  const int* vec = (const int*)d_in[6];
  const int* drev = (const int*)d_in[7];
  const int* dmap = (const int*)d_in[8];

  int* ws = (int*)d_ws;
  __hip_bfloat16* last_bf = (__hip_bfloat16*)(ws + WS_LAST_OFF);
  __hip_bfloat16* W_bf = last_bf + LAST_ELEMS;

  hipMemsetAsync(ws, 0, 64 * sizeof(int), stream);
  cvt_kernel<<<(LAST_ELEMS / 8 + 255) / 256, 256, 0, stream>>>(last, last_bf,
                                                               LAST_ELEMS / 8);
  cvt_kernel<<<(W_ELEMS / 8 + 255) / 256, 256, 0, stream>>>(W, W_bf, W_ELEMS / 8);
  count_kernel<<<TOT / 256, 256, 0, stream>>>(vec, dmap, ws);
  scan_kernel<<<1, 64, 0, stream>>>(ws);
  scatter_kernel<<<TOT / 256, 256, 0, stream>>>(vec, child_l, child_r, drev, dmap, ws);
  dim3 grid(ODIM / 128, (TOT + 127) / 128, NDIR);
  gemm_kernel<<<grid, 256, 0, stream>>>(bias, alpha, ws, (float*)d_out);
}

// Round 4
// 169.261 us; speedup vs baseline: 1.3983x; 1.3983x over previous
//
#include <hip/hip_runtime.h>
#include <hip/hip_bf16.h>

#define BB 8
#define LL 4096
#define NCH 8192
#define IDIM 256
#define KDIM 512
#define ODIM 512
#define NDIR 6
#define TOT (BB * LL)  // 32768

typedef short short8 __attribute__((ext_vector_type(8)));
typedef float floatx4 __attribute__((ext_vector_type(4)));

// ws layout:
//   ints [0..7]   cnt per dir
//   ints [8..15]  fill cursors
//   ints [16..23] off (compact exclusive scan)
//   ints [64 .. 64+TOT)        idx  (lin per bucketed row)
//   ints [64+TOT .. 64+2*TOT)  rows (r0 | r1<<16)
//   then bf16 last copy (33.5 MB), bf16 W copy (3.1 MB)  => ~37 MB total
#define WS_LAST_OFF (64 + 2 * TOT)
#define LAST_ELEMS (BB * NCH * IDIM)  // 16,777,216
#define W_ELEMS (NDIR * ODIM * KDIM)  // 1,572,864
#define N_LAST8 (LAST_ELEMS / 8)      // 2,097,152
#define N_W8 (W_ELEMS / 8)            // 196,608

__device__ inline void async_copy16(const void* g, void* l) {
  __builtin_amdgcn_global_load_lds(
      (const __attribute__((address_space(1))) void*)g,
      (__attribute__((address_space(3))) void*)l, 16, 0, 0);
}

__device__ inline void cvt8(const float* __restrict__ src,
                            __hip_bfloat16* __restrict__ dst, int i) {
  const floatx4* s = (const floatx4*)src;
  floatx4 a = s[2 * i];
  floatx4 b = s[2 * i + 1];
  union { short8 v; __hip_bfloat16 h[8]; } u;
  u.h[0] = __float2bfloat16(a[0]); u.h[1] = __float2bfloat16(a[1]);
  u.h[2] = __float2bfloat16(a[2]); u.h[3] = __float2bfloat16(a[3]);
  u.h[4] = __float2bfloat16(b[0]); u.h[5] = __float2bfloat16(b[1]);
  u.h[6] = __float2bfloat16(b[2]); u.h[7] = __float2bfloat16(b[3]);
  ((short8*)dst)[i] = u.v;
}

// ---- prep: cvt(last) + cvt(W) + dir histogram, fused (homogeneous blocks) ----
__global__ __launch_bounds__(256) void prep_kernel(
    const float* __restrict__ last, const float* __restrict__ W,
    const int* __restrict__ vec, const int* __restrict__ dmap,
    int* __restrict__ ws) {
  __hip_bfloat16* last_bf = (__hip_bfloat16*)(ws + WS_LAST_OFF);
  __hip_bfloat16* W_bf = last_bf + LAST_ELEMS;
  int gid = blockIdx.x * 256 + threadIdx.x;
  if (gid < N_LAST8) {
    cvt8(last, last_bf, gid);
  } else if (gid < N_LAST8 + N_W8) {
    cvt8(W, W_bf, gid - N_LAST8);
  } else {
    __shared__ int lcnt[8];
    int tid = threadIdx.x;
    if (tid < 8) lcnt[tid] = 0;
    __syncthreads();
    int lin = gid - (N_LAST8 + N_W8);
    int dir = dmap[vec[lin]] & 7;
    atomicAdd(&lcnt[dir], 1);
    __syncthreads();
    if (tid < 8 && lcnt[tid]) atomicAdd(&ws[tid], lcnt[tid]);
  }
}

// ---- scan: 8-entry exclusive scan (compact offsets) ----
__global__ void scan_kernel(int* __restrict__ ws) {
  if (threadIdx.x == 0) {
    int s = 0;
    for (int d = 0; d < 8; ++d) { ws[16 + d] = s; s += ws[d]; }
  }
}

// ---- scatter into compact buckets ----
__global__ __launch_bounds__(256) void scatter_kernel(
    const int* __restrict__ vec, const int* __restrict__ child_l,
    const int* __restrict__ child_r, const int* __restrict__ drev,
    const int* __restrict__ dmap, int* __restrict__ ws) {
  __shared__ int lcnt[8];
  __shared__ int gbase[8];
  int* fill = ws + 8;
  const int* base = ws + 16;
  int* idx = ws + 64;
  int* rows = ws + 64 + TOT;

  int tid = threadIdx.x;
  if (tid < 8) lcnt[tid] = 0;
  __syncthreads();

  int lin = blockIdx.x * 256 + tid;
  int l = lin & (LL - 1);
  int v = vec[lin];
  int dir = dmap[v] & 7;
  int sw = drev[v];
  int cl = child_l[l];
  int cr = child_r[l];
  int r0 = sw ? cr : cl;
  int r1 = sw ? cl : cr;
  int pos = atomicAdd(&lcnt[dir], 1);
  __syncthreads();
  if (tid < 8) gbase[tid] = lcnt[tid] ? atomicAdd(&fill[tid], lcnt[tid]) : 0;
  __syncthreads();
  int slot = base[dir] + gbase[dir] + pos;
  idx[slot] = lin;
  rows[slot] = r0 | (r1 << 16);
}

// ---- grouped GEMM: 128x128 tile, BK=64, global_load_lds staging, XOR swizzle -
// Block = 4 waves (2x2), each wave 64x64 via 4x4 mfma_f32_16x16x32_bf16.
// LDS layout: [row][64] bf16 (128 B/row); 16B-unit column XOR-swizzled by row&7
// (applied on the global-source side so staging stays lane-contiguous).
__global__ __launch_bounds__(256) void gemm_kernel(
    const float* __restrict__ bias, const float* __restrict__ alpha_m,
    const int* __restrict__ ws, float* __restrict__ out) {
  __shared__ __hip_bfloat16 Als[128 * 64];  // 16 KB
  __shared__ __hip_bfloat16 Bls[128 * 64];  // 16 KB

  // ---- tile -> dir mapping via 128-aligned tile ranges ----
  const int mt = blockIdx.y;
  const int nt = blockIdx.x;
  int d = -1, count = 0, off = 0, m_base = 0;
  {
    int tb = 0;
    for (int dd = 0; dd < NDIR; ++dd) {
      int c = ws[dd];
      int ntile = (c + 127) >> 7;
      if (mt < tb + ntile) { d = dd; count = c; off = ws[16 + dd]; m_base = (mt - tb) * 128; break; }
      tb += ntile;
    }
  }
  if (d < 0) return;

  const int* idx = ws + 64;
  const int* rows = ws + 64 + TOT;
  const __hip_bfloat16* last_bf = (const __hip_bfloat16*)(ws + WS_LAST_OFF);
  const __hip_bfloat16* W_bf = last_bf + LAST_ELEMS;

  const int tid = threadIdx.x;
  const int wave = __builtin_amdgcn_readfirstlane(tid >> 6);
  const int lane = tid & 63;
  const int lane15 = lane & 15;
  const int quad = lane >> 4;
  const int wm = wave >> 1;
  const int wn = wave & 1;
  const int n_blk = nt * 128;

  // ---- staging descriptors: per wave 4 A-instrs + 4 B-instrs, 8 rows each ----
  const __hip_bfloat16* ap0[4];
  const __hip_bfloat16* ap1[4];
  const __hip_bfloat16* bp[4];
  int ldsrow[4];
#pragma unroll
  for (int i = 0; i < 4; ++i) {
    int sr = wave * 32 + i * 8 + (lane >> 3);  // local row 0..127
    ldsrow[i] = (wave * 32 + i * 8) * 64;      // lds elem offset (wave-uniform)
    int lr = m_base + sr;
    if (lr >= count) lr = count - 1;  // clamp (tile exists => count>0)
    int lin = idx[off + lr] & (TOT - 1);
    int rr = rows[off + lr];
    int b = lin >> 12;
    int r0 = rr & (NCH - 1);
    int r1 = (rr >> 16) & (NCH - 1);
    int xu = ((lane & 7) ^ (sr & 7)) * 8;  // swizzled 16B-unit -> elems
    ap0[i] = last_bf + (long long)(b * NCH + r0) * IDIM + xu;
    ap1[i] = last_bf + (long long)(b * NCH + r1) * IDIM + xu;
    int xuB = xu;  // same lane/row pattern for B
    bp[i] = W_bf + (long long)(d * ODIM + n_blk + sr) * KDIM + xuB;
  }

  floatx4 acc[4][4] = {};
  const int lx = lane15 & 7;  // frag-read swizzle key (row&7 == lane15&7)

#pragma unroll
  for (int kt = 0; kt < 8; ++kt) {
    __syncthreads();  // previous chunk's reads complete before overwrite
    const int ko = (kt & 3) * 64;
#pragma unroll
    for (int i = 0; i < 4; ++i) {
      const __hip_bfloat16* ga = (kt < 4 ? ap0[i] : ap1[i]) + ko;
      async_copy16(ga, &Als[ldsrow[i]]);
    }
#pragma unroll
    for (int i = 0; i < 4; ++i) {
      async_copy16(bp[i] + kt * 64, &Bls[ldsrow[i]]);
    }
    __syncthreads();  // staging visible (compiler drains vmcnt before barrier)

#pragma unroll
    for (int s = 0; s < 2; ++s) {
      const int xcol = ((quad + 4 * s) ^ lx) * 8;  // swizzled elem offset
      short8 a[4], b[4];
#pragma unroll
      for (int i = 0; i < 4; ++i)
        a[i] = *(const short8*)&Als[(wm * 64 + i * 16 + lane15) * 64 + xcol];
#pragma unroll
      for (int j = 0; j < 4; ++j)
        b[j] = *(const short8*)&Bls[(wn * 64 + j * 16 + lane15) * 64 + xcol];
#pragma unroll
      for (int i = 0; i < 4; ++i)
#pragma unroll
        for (int j = 0; j < 4; ++j)
          acc[i][j] = __builtin_amdgcn_mfma_f32_16x16x32_bf16(a[i], b[j], acc[i][j], 0, 0, 0);
    }
  }

  // ---- epilogue: bias + leaky relu, scatter rows ----
  const float alpha = alpha_m[d];
  float bj[4];
#pragma unroll
  for (int j = 0; j < 4; ++j)
    bj[j] = bias[d * ODIM + n_blk + wn * 64 + j * 16 + lane15];

#pragma unroll
  for (int i = 0; i < 4; ++i) {
#pragma unroll
    for (int reg = 0; reg < 4; ++reg) {
      int row_id = m_base + wm * 64 + i * 16 + quad * 4 + reg;
      if (row_id >= count) continue;
      int lin = idx[off + row_id] & (TOT - 1);
      float* orow = out + (long long)lin * ODIM + n_blk + wn * 64;
#pragma unroll
      for (int j = 0; j < 4; ++j) {
        float y = acc[i][j][reg] + bj[j];
        y = y > 0.f ? y : alpha * y;
        orow[j * 16 + lane15] = y;
      }
    }
  }
}

extern "C" void kernel_launch(void* const* d_in, const int* in_sizes, int n_in,
                              void* d_out, int out_size, void* d_ws, size_t ws_size,
                              hipStream_t stream) {
  const float* last = (const float*)d_in[0];
  const float* W = (const float*)d_in[1];
  const float* bias = (const float*)d_in[2];
  const float* alpha = (const float*)d_in[3];
  const int* child_l = (const int*)d_in[4];
  const int* child_r = (const int*)d_in[5];
  const int* vec = (const int*)d_in[6];
  const int* drev = (const int*)d_in[7];
  const int* dmap = (const int*)d_in[8];

  int* ws = (int*)d_ws;

  hipMemsetAsync(ws, 0, 64 * sizeof(int), stream);
  int prep_blocks = (N_LAST8 + N_W8 + TOT) / 256;  // all regions 256-divisible
  prep_kernel<<<prep_blocks, 256, 0, stream>>>(last, W, vec, dmap, ws);
  scan_kernel<<<1, 64, 0, stream>>>(ws);
  scatter_kernel<<<TOT / 256, 256, 0, stream>>>(vec, child_l, child_r, drev, dmap, ws);
  // max tiles = 256 + (NDIR-1) from per-dir 128-padding
  dim3 grid(ODIM / 128, TOT / 128 + NDIR, 1);
  gemm_kernel<<<grid, 256, 0, stream>>>(bias, alpha, ws, (float*)d_out);
}